// Round 1
// baseline (715.483 us; speedup 1.0000x reference)
//
#include <hip/hip_runtime.h>

// out[m] = MLP(x[m,:]) where x = inputs^T, inputs is [RC=1024][BA=131072] f32.
// Layer 1 (the only heavy op) as f16 MFMA: C[M=131072, N=64] = x @ W1.
//
// Structure (v2 -- barrier-free K-loop):
//  - Block: 1024 threads = 16 waves, M_block = 512 (one 32-row tile per wave),
//    grid = 256 -> 1 block/CU (LDS-capped), 16 waves/CU.
//  - W1 staged ONCE into 128 KiB LDS as 128 pre-formed MFMA B-frags
//    (frag(ks,nt) at [(ks*2+nt)*64 + lane]*16B -> linear, conflict-free b128).
//  - Inputs (zero reuse!) go straight global->reg as A-frags: per k-step each
//    lane loads 8 k-strided f32 at its m (lanes 0..31 contiguous m = 128B
//    segments), cvt f16, MFMA. 2-deep ping-pong (xa/xb), NO barriers, NO
//    vmcnt(0) drains in the loop -> HBM latency pipelined across all of K.
//  - Epilogue: 2-pass LDS transpose (stride 33 -> conflict-free reads),
//    layers 2+3 fp32, d-reduction split across lane halves + shfl_xor(32).

#define RC 1024
#define BA 131072
#define D1 64
#define D2 16

#define MB 512            // m per block (16 waves * 32)
#define HS 33             // epilogue H row stride in dwords (33 mod 32 = 1)

using f16x8  = __attribute__((ext_vector_type(8))) _Float16;
using f32x16 = __attribute__((ext_vector_type(16))) float;

__global__ __launch_bounds__(1024, 4) void mlp3_mfma_v2(
    const float* __restrict__ inputs,
    const float* __restrict__ W1,
    const float* __restrict__ b1,
    const float* __restrict__ W2,
    const float* __restrict__ b2,
    const float* __restrict__ W3,
    const float* __restrict__ b3,
    float* __restrict__ out)
{
    // 128 KiB: all of W1 as f16 MFMA B-fragments. Reused as epilogue H buffer.
    __shared__ __align__(16) _Float16 smem[65536];
    f16x8* Wf = (f16x8*)smem;

    const int t  = threadIdx.x;
    const int l  = t & 63;
    const int wv = t >> 6;

    // ---- stage W1 -> LDS as pre-formed B-frags (once; 256 KB f32 read) ----
    // lane-frag lf: frag = lf>>6 (= ks*2+nt), lane = lf&63;
    // holds W1[ks*16 + (lane>>5)*8 + u][(lane&31) + 32*nt], u=0..7.
    #pragma unroll
    for (int i = 0; i < 8; ++i) {
        const int lf   = t + i * 1024;
        const int lane = lf & 63;
        const int frag = lf >> 6;
        const int ks   = frag >> 1;
        const int nt   = frag & 1;
        const int n    = (lane & 31) + 32 * nt;
        const int kb   = ks * 16 + (lane >> 5) * 8;
        float w8[8];
        #pragma unroll
        for (int u = 0; u < 8; ++u) w8[u] = W1[(size_t)(kb + u) * D1 + n];
        f16x8 h;
        #pragma unroll
        for (int u = 0; u < 8; ++u) h[u] = (_Float16)w8[u];
        Wf[lf] = h;
    }
    __syncthreads();   // the only pre-epilogue barrier in the kernel

    // ---- barrier-free K-loop: A straight to registers ----
    const int    mrow  = blockIdx.x * MB + wv * 32 + (l & 31);
    const size_t kstep = (size_t)16 * BA;
    const float* p0    = inputs + (size_t)((l >> 5) * 8) * BA + mrow;

    f32x16 acc0 = {};
    f32x16 acc1 = {};
    float xa[8], xb[8];

#define LD(X, P) { _Pragma("unroll") \
    for (int u = 0; u < 8; ++u) X[u] = (P)[(size_t)u * BA]; }

#define COMP(X, KS) { \
    f16x8 a; \
    _Pragma("unroll") for (int u = 0; u < 8; ++u) a[u] = (_Float16)X[u]; \
    f16x8 b0f = Wf[(KS) * 128 + l]; \
    f16x8 b1f = Wf[(KS) * 128 + 64 + l]; \
    acc0 = __builtin_amdgcn_mfma_f32_32x32x16_f16(a, b0f, acc0, 0, 0, 0); \
    acc1 = __builtin_amdgcn_mfma_f32_32x32x16_f16(a, b1f, acc1, 0, 0, 0); }

    LD(xa, p0);
    const float* p = p0 + kstep;
    for (int ks = 0; ks < 62; ks += 2) {
        LD(xb, p); p += kstep;
        COMP(xa, ks);
        LD(xa, p); p += kstep;
        COMP(xb, ks + 1);
    }
    LD(xb, p);
    COMP(xa, 62);
    COMP(xb, 63);
#undef LD
#undef COMP

    // ---- epilogue: 2-pass transpose via LDS, layers 2+3 in fp32 ----
    __syncthreads();   // everyone done reading Wf; smem becomes H
    float* Hw = (float*)smem + wv * (32 * HS);   // wave-private 32x33 region
    const int mc = l & 31;
    const int dh = l >> 5;     // which 16-d slice this lane accumulates

    float h2[D2];
    #pragma unroll
    for (int e = 0; e < D2; ++e) h2[e] = (dh == 0) ? b2[e] : 0.f;

    // C/D layout (32x32): col(n) = lane&31, row(m) = (r&3) + 8*(r>>2) + 4*(lane>>5)
#define EPI(ACC, DBASE) { \
    _Pragma("unroll") for (int r = 0; r < 16; ++r) { \
        const int mr = (r & 3) + 8 * (r >> 2) + 4 * dh; \
        Hw[mr * HS + mc] = ACC[r]; \
    } \
    asm volatile("s_waitcnt lgkmcnt(0)" ::: "memory"); \
    _Pragma("unroll") for (int dd = 0; dd < 16; ++dd) { \
        const int d = (DBASE) + dh * 16 + dd; \
        float h = Hw[mc * HS + dh * 16 + dd] + b1[d]; \
        h = h > 0.f ? h : 0.f; \
        _Pragma("unroll") for (int e = 0; e < D2; ++e) \
            h2[e] = fmaf(h, W2[d * D2 + e], h2[e]); \
    } \
    asm volatile("s_waitcnt lgkmcnt(0)" ::: "memory"); }

    EPI(acc0, 0)    // d = 0..31
    EPI(acc1, 32)   // d = 32..63
#undef EPI

    #pragma unroll
    for (int e = 0; e < D2; ++e) h2[e] += __shfl_xor(h2[e], 32, 64);

    float o = b3[0];
    #pragma unroll
    for (int e = 0; e < D2; ++e) {
        float h = h2[e] > 0.f ? h2[e] : 0.f;
        o = fmaf(h, W3[e], o);
    }
    if (l < 32)
        out[blockIdx.x * MB + wv * 32 + mc] = o;
}

extern "C" void kernel_launch(void* const* d_in, const int* in_sizes, int n_in,
                              void* d_out, int out_size, void* d_ws, size_t ws_size,
                              hipStream_t stream) {
    const float* inputs = (const float*)d_in[0];
    const float* W1     = (const float*)d_in[1];
    const float* b1     = (const float*)d_in[2];
    const float* W2     = (const float*)d_in[3];
    const float* b2     = (const float*)d_in[4];
    const float* W3     = (const float*)d_in[5];
    const float* b3     = (const float*)d_in[6];
    float* out = (float*)d_out;

    dim3 block(1024);
    dim3 grid(BA / MB);   // 256 blocks -> 1 per CU
    mlp3_mfma_v2<<<grid, block, 0, stream>>>(inputs, W1, b1, W2, b2, W3, b3, out);
}

// Round 3
// 715.480 us; speedup vs baseline: 1.0000x; 1.0000x over previous
//
#include <hip/hip_runtime.h>

// out[m] = MLP(x[m,:]) where x = inputs^T, inputs is [RC=1024][BA=131072] f32.
// Layer 1 as f16 MFMA: C[M=131072, N=64] = x @ W1.
//
// v3 — stream-quality global loads + k-major LDS + counted-vmcnt 2-phase:
//  - 512 thr (8 waves), MB=256, grid 512 (2 blocks/CU, 16 waves/CU, 72 KiB LDS).
//  - A staged per 32-k chunk with dwordx4: each wave reads 1 KiB-contiguous
//    row segments (the fill's proven 6.4 TB/s pattern), writes k-major
//    Ash[k][256] f32 (1 KiB rows -> full-BW b128 writes; frag reads
//    Ash[k][w*32+ln] hit 32 distinct banks -> conflict-free).
//  - W1 chunk staged as pre-formed f16 B-frags (4 KiB, L2-hot).
//  - 2-phase pipeline, ONE barrier per chunk = lgkmcnt(0) + raw s_barrier
//    (NO vmcnt drain -- prefetch loads stay in flight across the barrier;
//    compiler inserts counted vmcnt before the ds_writes that consume them).
//  - f32->f16 cvt at frag-build time. Epilogue: per-wave 32x33 transpose,
//    layers 2+3 fp32, halves combined via shfl_xor(32).

#define RC 1024
#define BA 131072
#define D1 64
#define D2 16

#define MB  256           // m per block
#define KC  32            // k per chunk
#define NCH (RC / KC)     // 32 chunks
#define HS  33            // epilogue H row stride (f32)

using f16x8  = __attribute__((ext_vector_type(8))) _Float16;
using f32x16 = __attribute__((ext_vector_type(16))) float;

__global__ __launch_bounds__(512, 4) void mlp3_mfma_v3(
    const float* __restrict__ inputs,
    const float* __restrict__ W1,
    const float* __restrict__ b1,
    const float* __restrict__ W2,
    const float* __restrict__ b2,
    const float* __restrict__ W3,
    const float* __restrict__ b3,
    float* __restrict__ out)
{
    __shared__ __align__(16) float Ash[2][KC][MB];   // 64 KiB, k-major
    __shared__ __align__(16) f16x8 Wsh[2][4][64];    // 8 KiB: frag(ks,nt)[lane]

    const int t  = threadIdx.x;
    const int l  = t & 63;
    const int w  = t >> 6;        // wave 0..7
    const int ln = l & 31;
    const int hi = l >> 5;
    const int mBase = blockIdx.x * MB;

    // W-staging role (threads 0..255): one frag-slot each
    const int wfrag = t >> 6;             // 0..3 (valid when t<256)
    const int wks   = t >> 7;             // 0..1
    const int wnt   = (t >> 6) & 1;
    const int wlane = t & 63;
    const int wn    = (wlane & 31) + 32 * wnt;
    const int wkb   = wks * 16 + (wlane >> 5) * 8;

    float4 xr0, xr1, xr2, xr3;    // A prefetch regs (static names)
    float  wr[8];                 // W prefetch regs (t<256)

#define LOADA(c) { \
    const float* p_ = inputs + (size_t)((c) * KC + w * 4) * BA + (mBase + (l << 2)); \
    xr0 = *(const float4*)(p_); \
    xr1 = *(const float4*)(p_ + (size_t)BA); \
    xr2 = *(const float4*)(p_ + (size_t)2 * BA); \
    xr3 = *(const float4*)(p_ + (size_t)3 * BA); }

#define LOADW(c) { if (t < 256) { \
    const float* q_ = W1 + (size_t)((c) * KC + wkb) * D1 + wn; \
    _Pragma("unroll") for (int u = 0; u < 8; ++u) wr[u] = q_[(size_t)u * D1]; } }

#define WRITE(b) { \
    { float* d_ = &Ash[b][w * 4][l << 2]; \
      *(float4*)(d_)          = xr0; \
      *(float4*)(d_ + MB)     = xr1; \
      *(float4*)(d_ + 2 * MB) = xr2; \
      *(float4*)(d_ + 3 * MB) = xr3; } \
    if (t < 256) { \
      f16x8 h_; \
      _Pragma("unroll") for (int u = 0; u < 8; ++u) h_[u] = (_Float16)wr[u]; \
      Wsh[b][wfrag][wlane] = h_; } }

    // lgkmcnt-only barrier: LDS drained, global prefetch stays in flight.
#define BAR() { asm volatile("s_waitcnt lgkmcnt(0)" ::: "memory"); \
                __builtin_amdgcn_s_barrier(); \
                __builtin_amdgcn_sched_barrier(0); }

    f32x16 acc0 = {};
    f32x16 acc1 = {};

#define COMPUTE(b) { \
    _Pragma("unroll") for (int ks = 0; ks < 2; ++ks) { \
      float av[8]; \
      _Pragma("unroll") for (int u = 0; u < 8; ++u) \
        av[u] = Ash[b][ks * 16 + hi * 8 + u][w * 32 + ln]; \
      f16x8 a_; \
      _Pragma("unroll") for (int u = 0; u < 8; ++u) a_[u] = (_Float16)av[u]; \
      f16x8 b0_ = Wsh[b][ks * 2 + 0][l]; \
      f16x8 b1_ = Wsh[b][ks * 2 + 1][l]; \
      acc0 = __builtin_amdgcn_mfma_f32_32x32x16_f16(a_, b0_, acc0, 0, 0, 0); \
      acc1 = __builtin_amdgcn_mfma_f32_32x32x16_f16(a_, b1_, acc1, 0, 0, 0); \
    } }

    // ---- prologue: chunk 0 staged, chunk 1 in flight ----
    LOADA(0); LOADW(0);
    WRITE(0);                       // compiler waits vmcnt for reg deps
    LOADA(1); LOADW(1);
    BAR();

    // ---- main loop: one lgkm-barrier per chunk, vmcnt never drained ----
    for (int c = 0; c < NCH; ++c) {
        const int cur = c & 1;
        if (c + 1 < NCH) { WRITE(cur ^ 1); }          // chunk c+1 -> other buf
        if (c + 2 < NCH) { LOADA(c + 2); LOADW(c + 2); }  // issue, no wait
        COMPUTE(cur);
        BAR();
    }
#undef LOADA
#undef LOADW
#undef WRITE
#undef COMPUTE

    // ---- epilogue: per-wave 32x33 transpose, layers 2+3 fp32 ----
    float* Hw = (float*)Ash + w * (32 * HS);   // wave-private, 8*4224 B < 64 KiB
    const int mc = ln;
    const int dh = hi;

    float h2[D2];
    #pragma unroll
    for (int e = 0; e < D2; ++e) h2[e] = (dh == 0) ? b2[e] : 0.f;

    // C/D layout (32x32): col(n)=lane&31, row(m)=(r&3)+8*(r>>2)+4*(lane>>5)
#define EPI(ACC, DBASE) { \
    _Pragma("unroll") for (int r = 0; r < 16; ++r) { \
        const int mr = (r & 3) + 8 * (r >> 2) + 4 * dh; \
        Hw[mr * HS + mc] = ACC[r]; \
    } \
    asm volatile("s_waitcnt lgkmcnt(0)" ::: "memory"); \
    __builtin_amdgcn_sched_barrier(0); \
    _Pragma("unroll") for (int dd = 0; dd < 16; ++dd) { \
        const int d = (DBASE) + dh * 16 + dd; \
        float h = Hw[mc * HS + dh * 16 + dd] + b1[d]; \
        h = h > 0.f ? h : 0.f; \
        _Pragma("unroll") for (int e = 0; e < D2; ++e) \
            h2[e] = fmaf(h, W2[d * D2 + e], h2[e]); \
    } \
    asm volatile("s_waitcnt lgkmcnt(0)" ::: "memory"); \
    __builtin_amdgcn_sched_barrier(0); }

    EPI(acc0, 0)    // d = 0..31
    EPI(acc1, 32)   // d = 32..63
#undef EPI
#undef BAR

    #pragma unroll
    for (int e = 0; e < D2; ++e) h2[e] += __shfl_xor(h2[e], 32, 64);

    float o = b3[0];
    #pragma unroll
    for (int e = 0; e < D2; ++e) {
        float h = h2[e] > 0.f ? h2[e] : 0.f;
        o = fmaf(h, W3[e], o);
    }
    if (l < 32)
        out[mBase + w * 32 + mc] = o;
}

extern "C" void kernel_launch(void* const* d_in, const int* in_sizes, int n_in,
                              void* d_out, int out_size, void* d_ws, size_t ws_size,
                              hipStream_t stream) {
    const float* inputs = (const float*)d_in[0];
    const float* W1     = (const float*)d_in[1];
    const float* b1     = (const float*)d_in[2];
    const float* W2     = (const float*)d_in[3];
    const float* b2     = (const float*)d_in[4];
    const float* W3     = (const float*)d_in[5];
    const float* b3     = (const float*)d_in[6];
    float* out = (float*)d_out;

    dim3 block(512);
    dim3 grid(BA / MB);   // 512 blocks
    mlp3_mfma_v3<<<grid, block, 0, stream>>>(inputs, W1, b1, W2, b2, W3, b3, out);
}